// Round 1
// baseline (978.012 us; speedup 1.0000x reference)
//
#include <hip/hip_runtime.h>
#include <cmath>

// Persistent weight-stationary LSTM decode. B=64, H=2048, steps=30.
// gates_t = W_sum @ h_t (t>=1, since x_t == h_t), W_hh @ h_0 at t=0.
// One block per CU (grid=256); weights live in LDS as fp16 MFMA A-frags.
//
// v6 restructure (this round):
//  - 8-way k-split: wave w owns k in [w*256,(w+1)*256) x ALL 4 n-tiles
//    (8 f32x4 accumulators). Each Wlds fragment is read exactly once per
//    step (was 2x: paired waves duplicated A-frag reads), halving the
//    LDS-pipe cost of the MFMA phase.
//  - Reduction via ds_add_f32 (atomicAdd on LDS) into a DOUBLE-BUFFERED,
//    bias-pre-initialized gates buffer with padded stride 68 (2 lanes/bank
//    = conflict-free). Replaces the 3-barrier red4 tree + writeback pass.
//    Barriers per step: 4 -> 2.
//  - Bias re-init of the other parity buffer done by waves 1-7 during the
//    pointwise phase (off critical path). Buffer parity hazards are
//    separated by the two per-step barriers (traced: reads of buf p at
//    step t complete before #2(t); next writes to p happen after #2(t+1)).
//  - c lives in a per-thread register (thread (w,lane) owns unit w, batch
//    lane across all steps). tanh via __expf (no libm tanhf).
//  - Per-wave spin now covers only 32 producer blocks (finer slices).
//  - Last-step h publish + vmcnt + flag skipped (slot 30 has no reader).
// Sync scheme unchanged: agent-scope relaxed atomic h stores, vmcnt(0),
// per-block flag, first-touch reads of a fresh 256KB slot per step.

#define HID   2048
#define BATCH 64
#define G4    8192
#define NCU   256                 // persistent grid size == CU count
#define HGRP  (HID * BATCH / 8)   // half8 groups per h slot
#define GSTR  68                  // padded gates row stride (words)
#define GWORDS (32 * GSTR)        // one gates buffer (2176 words)

typedef __attribute__((ext_vector_type(8))) _Float16 half8;
typedef __attribute__((ext_vector_type(4))) float f32x4;

// LDS layout (bytes):
//   [0,      131072)  Wlds   : half8 frags [(mt*64+kt)*64+lane]
//   [131072, 148480)  gbuf   : f32 [2][32][GSTR]  (double-buffered gates)
//   [148480, 149504)  hstage : f16 [64 batch][8 units]
//   [149504, 151552)  ybuf   : f32 [8 units][64 batch]
#define LDS_BYTES 151552

// ---- init: pack token -> h slot 0 (B-fragment layout), bsum, barrier flags ----
__global__ void k_init(const float* __restrict__ token, const float* __restrict__ bih,
                       const float* __restrict__ bhh, half8* __restrict__ h0p,
                       float* __restrict__ bsum, unsigned* __restrict__ flags) {
    int g = blockIdx.x * 256 + threadIdx.x;          // [0, 16384)
    int l = g & 63, nt = (g >> 6) & 3, kt = g >> 8;
    int n = nt * 16 + (l & 15);
    int k0 = kt * 32 + (l >> 4) * 8;
    const float4* ps = (const float4*)(token + (size_t)n * HID + k0);
    float4 a = ps[0], b = ps[1];
    half8 v;
    v[0]=(_Float16)a.x; v[1]=(_Float16)a.y; v[2]=(_Float16)a.z; v[3]=(_Float16)a.w;
    v[4]=(_Float16)b.x; v[5]=(_Float16)b.y; v[6]=(_Float16)b.z; v[7]=(_Float16)b.w;
    h0p[g] = v;
    if (g < G4) bsum[g] = bih[g] + bhh[g];
    if (g < NCU) flags[g] = 0u;
}

// ---- the persistent kernel ----
__global__ __launch_bounds__(512, 2)
void k_lstm(const float* __restrict__ wih, const float* __restrict__ whh,
            const float* __restrict__ bsum, const float* __restrict__ wout,
            _Float16* __restrict__ hbuf,     // (steps+1) slots, fragment layout
            float* __restrict__ ypart,       // [steps][NCU][64]
            unsigned* __restrict__ flags, int steps) {
    extern __shared__ char smem[];
    half8*     Wlds   = (half8*)smem;
    float*     gbuf   = (float*)(smem + 131072);
    _Float16*  hstage = (_Float16*)(smem + 148480);
    float*     ybuf   = (float*)(smem + 149504);

    const int tid  = threadIdx.x;
    const int blk  = blockIdx.x;
    const int lane = tid & 63;
    const int w    = tid >> 6;        // wave 0..7 = k-slice (256 k each)

    // prologue: stage W_hh rows for this block's 32 gate-rows as fp16 A-frags
    for (int idx = tid; idx < 2 * 64 * 64; idx += 512) {
        int l = idx & 63, kt = (idx >> 6) & 63, m2 = idx >> 12;
        int m = l & 15;
        int gate = m2 * 2 + (m >> 3);
        int row  = gate * HID + blk * 8 + (m & 7);
        int col  = kt * 32 + (l >> 4) * 8;
        const float4* p = (const float4*)(whh + (size_t)row * HID + col);
        float4 a = p[0], b = p[1];
        half8 v;
        v[0]=(_Float16)a.x; v[1]=(_Float16)a.y; v[2]=(_Float16)a.z; v[3]=(_Float16)a.w;
        v[4]=(_Float16)b.x; v[5]=(_Float16)b.y; v[6]=(_Float16)b.z; v[7]=(_Float16)b.w;
        Wlds[idx] = v;
    }

    // prologue: bias-init gbuf[0] (consumed by step 0's ds_adds)
    #pragma unroll
    for (int j = 0; j < 4; ++j) {
        int li  = tid + j * 512;                     // [0, 2048)
        int row = li >> 6;                           // gates row 0..31
        int mt = row >> 4, m16 = row & 15;
        int gate = mt * 2 + (m16 >> 3);
        gbuf[row * GSTR + (li & 63)] = bsum[gate * HID + blk * 8 + (m16 & 7)];
    }

    // per-thread constants / state
    const float wj = wout[blk * 8 + w];   // this wave's output weight (unit w)
    float creg = 0.0f;                    // c state: unit w, batch lane

    // re-init constants for the OTHER gates buffer (waves 1..7 own this job)
    float bvr[5]; int bar[5];
    if (w > 0) {
        int idx = tid - 64;                          // [0, 448)
        #pragma unroll
        for (int j = 0; j < 5; ++j) {
            int li  = idx + j * 448;
            int row = (li >> 6) & 31;
            int mt = row >> 4, m16 = row & 15;
            int gate = mt * 2 + (m16 >> 3);
            bar[j] = (li < 2048) ? (row * GSTR + (li & 63)) : -1;
            bvr[j] = (li < 2048) ? bsum[gate * HID + blk * 8 + (m16 & 7)] : 0.0f;
        }
    }
    __syncthreads();

    for (int t = 0; t < steps; ++t) {
        if (t) {
            // per-slice wait: wave w consumes k units [w*256,(w+1)*256)
            // = producer blocks [w*32, w*32+32). Lane li waits flags[w*32+(li&31)].
            while (__hip_atomic_load(&flags[w * 32 + (lane & 31)], __ATOMIC_RELAXED,
                                     __HIP_MEMORY_SCOPE_AGENT) < (unsigned)t)
                __builtin_amdgcn_s_sleep(1);
            asm volatile("" ::: "memory");   // no h loads hoisted above the spin
        }
        const half8* hp = (const half8*)(hbuf + (size_t)t * HID * BATCH);
        // 8 accumulators: (mt 0..1) x (nt 0..3), k-range [w*256,(w+1)*256)
        f32x4 a0[4] = {{0,0,0,0},{0,0,0,0},{0,0,0,0},{0,0,0,0}};
        f32x4 a1[4] = {{0,0,0,0},{0,0,0,0},{0,0,0,0},{0,0,0,0}};
        #pragma unroll
        for (int kk = 0; kk < 8; ++kk) {
            const int kt = w * 8 + kk;
            half8 av0 = Wlds[(kt) * 64 + lane];            // mt=0 (read once/step)
            half8 av1 = Wlds[(64 + kt) * 64 + lane];       // mt=1
            half8 b0  = hp[(kt * 4 + 0) * 64 + lane];
            half8 b1  = hp[(kt * 4 + 1) * 64 + lane];
            half8 b2  = hp[(kt * 4 + 2) * 64 + lane];
            half8 b3  = hp[(kt * 4 + 3) * 64 + lane];
            a0[0] = __builtin_amdgcn_mfma_f32_16x16x32_f16(av0, b0, a0[0], 0, 0, 0);
            a0[1] = __builtin_amdgcn_mfma_f32_16x16x32_f16(av0, b1, a0[1], 0, 0, 0);
            a0[2] = __builtin_amdgcn_mfma_f32_16x16x32_f16(av0, b2, a0[2], 0, 0, 0);
            a0[3] = __builtin_amdgcn_mfma_f32_16x16x32_f16(av0, b3, a0[3], 0, 0, 0);
            a1[0] = __builtin_amdgcn_mfma_f32_16x16x32_f16(av1, b0, a1[0], 0, 0, 0);
            a1[1] = __builtin_amdgcn_mfma_f32_16x16x32_f16(av1, b1, a1[1], 0, 0, 0);
            a1[2] = __builtin_amdgcn_mfma_f32_16x16x32_f16(av1, b2, a1[2], 0, 0, 0);
            a1[3] = __builtin_amdgcn_mfma_f32_16x16x32_f16(av1, b3, a1[3], 0, 0, 0);
        }
        // 8-way k-split reduction: ds_add_f32 into bias-pre-initialized gates.
        // addr = row*68 + col -> bank = (4*row + col) & 31: per instr lanes land
        // 2/bank (free, m136). Gates row = mt*16 + (lane>>4)*4 + r, col = nt*16+(lane&15).
        float* Gc = gbuf + (t & 1) * GWORDS;
        {
            const int q4 = (lane >> 4) * 4, c16 = lane & 15;
            #pragma unroll
            for (int nt = 0; nt < 4; ++nt) {
                #pragma unroll
                for (int r = 0; r < 4; ++r) {
                    atomicAdd(&Gc[(q4 + r) * GSTR + nt * 16 + c16],      a0[nt][r]);
                    atomicAdd(&Gc[(16 + q4 + r) * GSTR + nt * 16 + c16], a1[nt][r]);
                }
            }
        }
        __syncthreads();                       // #1: gates complete
        // pointwise: wave w = local unit w, lane = batch b; c in register
        {
            float gi = Gc[( 0 + w) * GSTR + lane];
            float gf = Gc[( 8 + w) * GSTR + lane];
            float gg = Gc[(16 + w) * GSTR + lane];
            float go = Gc[(24 + w) * GSTR + lane];
            float iv = 1.0f / (1.0f + __expf(-gi));
            float fv = 1.0f / (1.0f + __expf(-gf));
            float eg = __expf(2.0f * gg);
            float gv = 1.0f - 2.0f / (eg + 1.0f);          // tanh(gg)
            float ov = 1.0f / (1.0f + __expf(-go));
            creg = fv * creg + iv * gv;
            float ec = __expf(2.0f * creg);
            float th = 1.0f - 2.0f / (ec + 1.0f);          // tanh(c)
            float hv = ov * th;
            hstage[lane * 8 + w] = (_Float16)hv;    // [b][unit], 16 B per batch row
            ybuf[w * 64 + lane]  = hv * wj;
        }
        // waves 1-7: bias-re-init the other parity buffer (for step t+1),
        // in the shadow of the pointwise phase. Safe window: after #1(t)
        // (prev reader of this buffer finished before it) and before #2(t)
        // (next ds_adds to it start after #2(t)).
        if (w > 0 && t < steps - 1) {
            float* GN = gbuf + ((t + 1) & 1) * GWORDS;
            #pragma unroll
            for (int j = 0; j < 5; ++j)
                if (bar[j] >= 0) GN[bar[j]] = bvr[j];
        }
        __syncthreads();                       // #2: hstage ready, next buffer inited
        if (w == 0) {
            const int b = lane;
            if (t < steps - 1) {
                // publish h for batch b: this block's 8 units = 16 contiguous
                // bytes of the B-fragment half8 group. Two 8-byte agent-scope
                // relaxed atomic stores (coherence point, no L2 residency).
                const int kt2 = blk >> 2, quad = blk & 3;       // fixed per block
                const int nt2 = b >> 4, lp = quad * 16 + (b & 15);
                const size_t g = (size_t)(kt2 * 4 + nt2) * 64 + lp;
                unsigned long long* dst = (unsigned long long*)
                    (hbuf + (size_t)(t + 1) * HID * BATCH + g * 8);
                const unsigned long long* src =
                    (const unsigned long long*)(hstage + b * 8);
                unsigned long long v0 = src[0], v1 = src[1];
                __hip_atomic_store(dst,     v0, __ATOMIC_RELAXED, __HIP_MEMORY_SCOPE_AGENT);
                __hip_atomic_store(dst + 1, v1, __ATOMIC_RELAXED, __HIP_MEMORY_SCOPE_AGENT);
                asm volatile("s_waitcnt vmcnt(0)" ::: "memory");  // h at coherence point
                if (lane == 0)
                    __hip_atomic_store(&flags[blk], (unsigned)(t + 1),
                                       __ATOMIC_RELAXED, __HIP_MEMORY_SCOPE_AGENT);
            }
            // y partial (after flag release: off the critical path)
            float s = ybuf[lane];
            #pragma unroll
            for (int u = 1; u < 8; ++u) s += ybuf[u * 64 + lane];
            ypart[((size_t)t * NCU + blk) * 64 + lane] = s;
        }
        if (t == 0) {
            // upgrade Wlds in place: W_hh -> W_sum (+= W_ih); must complete in
            // ALL waves before any wave's step-1 MFMA -> block barrier after.
            for (int idx = tid; idx < 2 * 64 * 64; idx += 512) {
                int l = idx & 63, kt = (idx >> 6) & 63, m2 = idx >> 12;
                int m = l & 15;
                int gate = m2 * 2 + (m >> 3);
                int row  = gate * HID + blk * 8 + (m & 7);
                int col  = kt * 32 + (l >> 4) * 8;
                const float4* p = (const float4*)(wih + (size_t)row * HID + col);
                float4 a = p[0], b = p[1];
                half8 v = Wlds[idx];
                v[0] = (_Float16)((float)v[0] + a.x); v[1] = (_Float16)((float)v[1] + a.y);
                v[2] = (_Float16)((float)v[2] + a.z); v[3] = (_Float16)((float)v[3] + a.w);
                v[4] = (_Float16)((float)v[4] + b.x); v[5] = (_Float16)((float)v[5] + b.y);
                v[6] = (_Float16)((float)v[6] + b.z); v[7] = (_Float16)((float)v[7] + b.w);
                Wlds[idx] = v;
            }
            __syncthreads();
        }
    }
}

// ---- final: out[b][t] = bout + sum over 256 CU partials ----
__global__ __launch_bounds__(512)
void k_yout(const float* __restrict__ ypart, const float* __restrict__ bout,
            float* __restrict__ out, int steps) {
    __shared__ float red[8][64];
    int t = blockIdx.x;
    int tid = threadIdx.x;
    int b = tid & 63, ch = tid >> 6;               // 8 chunks x 32 CUs
    const float* p = ypart + (size_t)t * NCU * 64 + b;
    float s = 0.0f;
    #pragma unroll 8
    for (int cu = ch * 32; cu < ch * 32 + 32; ++cu) s += p[(size_t)cu * 64];
    red[ch][b] = s;
    __syncthreads();
    if (tid < 64) {
        float r = bout[0];
        #pragma unroll
        for (int u = 0; u < 8; ++u) r += red[u][tid];
        out[(size_t)tid * steps + t] = r;
    }
}

extern "C" void kernel_launch(void* const* d_in, const int* in_sizes, int n_in,
                              void* d_out, int out_size, void* d_ws, size_t ws_size,
                              hipStream_t stream) {
    const float* token = (const float*)d_in[0];
    const float* wih   = (const float*)d_in[2];
    const float* whh   = (const float*)d_in[3];
    const float* bih   = (const float*)d_in[4];
    const float* bhh   = (const float*)d_in[5];
    const float* wout  = (const float*)d_in[6];
    const float* bout  = (const float*)d_in[7];
    float* out = (float*)d_out;
    const int steps = out_size / BATCH;            // 30

    char* ws = (char*)d_ws;
    size_t off = 0;
    auto carve = [&](size_t bytes) -> void* {
        void* p = ws + off;
        off = (off + bytes + 255) & ~(size_t)255;
        return p;
    };
    _Float16* hbuf  = (_Float16*)carve((size_t)(steps + 1) * HID * BATCH * 2); // ~8 MB
    float*    bsum  = (float*)carve((size_t)G4 * 4);                   // 32 KB
    float*    ypart = (float*)carve((size_t)steps * NCU * 64 * 4);     // ~2 MB
    unsigned* flags = (unsigned*)carve(NCU * 4);

    hipFuncSetAttribute(reinterpret_cast<const void*>(&k_lstm),
                        hipFuncAttributeMaxDynamicSharedMemorySize, LDS_BYTES);

    k_init<<<dim3(HGRP / 256), dim3(256), 0, stream>>>(
        token, bih, bhh, (half8*)hbuf, bsum, flags);

    k_lstm<<<dim3(NCU), dim3(512), LDS_BYTES, stream>>>(
        wih, whh, bsum, wout, hbuf, ypart, flags, steps);

    k_yout<<<dim3(steps), dim3(512), 0, stream>>>(ypart, bout, out, steps);
}

// Round 2
// 449.667 us; speedup vs baseline: 2.1750x; 2.1750x over previous
//
#include <hip/hip_runtime.h>
#include <cmath>

// Persistent weight-stationary LSTM decode. B=64, H=2048, steps=30.
// gates_t = W_sum @ h_t (t>=1, since x_t == h_t), W_hh @ h_0 at t=0.
// One block per CU (grid=256); weights live in LDS as fp16 MFMA A-frags.
// Sync v5 skeleton (verified 439.7us): zero cache-maintenance + PER-SLICE flag
// waiting -- wave with k-slice ks spins on just its 64 producer flags and
// starts MFMA as soon as its slice is published.
//
// v7 = v5 + three disasm-safe micro-opts (v6 post-mortem: LDS float atomicAdd
// lowered to latency-bound RMW chains, +543us -- NEVER use fp atomics on LDS
// from HIP source without verifying the lowering):
//  - c state in a per-thread register (thread (w,lane) owns unit w, batch
//    lane across all steps); cbuf LDS region removed.
//  - tanh via __expf: 1 - 2/(exp(2x)+1)  (no libm tanhf expansion).
//  - last-step h publish + vmcnt(0) drain + flag store skipped (slot 30
//    has no reader; ypart still written).

#define HID   2048
#define BATCH 64
#define G4    8192
#define NCU   256                 // persistent grid size == CU count
#define HGRP  (HID * BATCH / 8)   // half8 groups per h slot

typedef __attribute__((ext_vector_type(8))) _Float16 half8;
typedef __attribute__((ext_vector_type(4))) float f32x4;

// LDS layout (bytes):
//   [0,      131072)  Wlds   : half8 frags [(mt*64+kt)*64+lane]
//   [131072, 139264)  gates  : f32 [32 rows][64 batch]
//   [139264, 155648)  red    : f32x4 [(srow*4+p)*64+lane]  (4 srows)
//   [155648, 156672)  hstage : f16 [64 batch][8 units]
//   [156672, 158720)  ybuf   : f32 [8 units][64 batch]
#define LDS_BYTES 158720

// ---- init: pack token -> h slot 0 (B-fragment layout), bsum, barrier flags ----
__global__ void k_init(const float* __restrict__ token, const float* __restrict__ bih,
                       const float* __restrict__ bhh, half8* __restrict__ h0p,
                       float* __restrict__ bsum, unsigned* __restrict__ flags) {
    int g = blockIdx.x * 256 + threadIdx.x;          // [0, 16384)
    int l = g & 63, nt = (g >> 6) & 3, kt = g >> 8;
    int n = nt * 16 + (l & 15);
    int k0 = kt * 32 + (l >> 4) * 8;
    const float4* ps = (const float4*)(token + (size_t)n * HID + k0);
    float4 a = ps[0], b = ps[1];
    half8 v;
    v[0]=(_Float16)a.x; v[1]=(_Float16)a.y; v[2]=(_Float16)a.z; v[3]=(_Float16)a.w;
    v[4]=(_Float16)b.x; v[5]=(_Float16)b.y; v[6]=(_Float16)b.z; v[7]=(_Float16)b.w;
    h0p[g] = v;
    if (g < G4) bsum[g] = bih[g] + bhh[g];
    if (g < NCU) flags[g] = 0u;
}

// ---- the persistent kernel ----
__global__ __launch_bounds__(512, 2)
void k_lstm(const float* __restrict__ wih, const float* __restrict__ whh,
            const float* __restrict__ bsum, const float* __restrict__ wout,
            _Float16* __restrict__ hbuf,     // (steps+1) slots, fragment layout
            float* __restrict__ ypart,       // [steps][NCU][64]
            unsigned* __restrict__ flags, int steps) {
    extern __shared__ char smem[];
    half8*     Wlds   = (half8*)smem;
    float*     gates  = (float*)(smem + 131072);
    f32x4*     red4   = (f32x4*)(smem + 139264);
    _Float16*  hstage = (_Float16*)(smem + 155648);
    float*     ybuf   = (float*)(smem + 156672);

    const int tid  = threadIdx.x;
    const int blk  = blockIdx.x;
    const int lane = tid & 63;
    const int w    = tid >> 6;        // wave 0..7
    const int half = w & 1;           // n-tile pair: nt in {2*half, 2*half+1}
    const int ks   = w >> 1;          // k-split slice 0..3 (512 k each)

    // prologue: stage W_hh rows for this block's 32 gate-rows as fp16 A-frags
    for (int idx = tid; idx < 2 * 64 * 64; idx += 512) {
        int l = idx & 63, kt = (idx >> 6) & 63, m2 = idx >> 12;
        int m = l & 15;
        int gate = m2 * 2 + (m >> 3);
        int row  = gate * HID + blk * 8 + (m & 7);
        int col  = kt * 32 + (l >> 4) * 8;
        const float4* p = (const float4*)(whh + (size_t)row * HID + col);
        float4 a = p[0], b = p[1];
        half8 v;
        v[0]=(_Float16)a.x; v[1]=(_Float16)a.y; v[2]=(_Float16)a.z; v[3]=(_Float16)a.w;
        v[4]=(_Float16)b.x; v[5]=(_Float16)b.y; v[6]=(_Float16)b.z; v[7]=(_Float16)b.w;
        Wlds[idx] = v;
    }

    // bias for the gates-writeback waves (ks==0), both m-tiles
    float bias_r[2][4];
    if (ks == 0) {
        const int q = lane >> 4;
        #pragma unroll
        for (int mt2 = 0; mt2 < 2; ++mt2)
            #pragma unroll
            for (int r = 0; r < 4; ++r) {
                int m16 = q * 4 + r;
                bias_r[mt2][r] = bsum[(mt2 * 2 + (m16 >> 3)) * HID + blk * 8 + (m16 & 7)];
            }
    }
    const float wj = wout[blk * 8 + w];   // this wave's output weight (unit j)
    float creg = 0.0f;                    // c state: unit w, batch lane (register)
    __syncthreads();

    for (int t = 0; t < steps; ++t) {
        const half8* hp = (const half8*)(hbuf + (size_t)t * HID * BATCH);
        // acc: covering (mt, nt=2*half+j)
        f32x4 a00 = {0,0,0,0}, a01 = {0,0,0,0}, a10 = {0,0,0,0}, a11 = {0,0,0,0};
        const int ktb = ks * 16;
        #pragma unroll
        for (int kk = 0; kk < 16; ++kk) {
            int kt = ktb + kk;
            half8 av0 = Wlds[(kt) * 64 + lane];            // mt=0
            half8 av1 = Wlds[(64 + kt) * 64 + lane];       // mt=1
            half8 b0  = hp[(kt * 4 + half * 2 + 0) * 64 + lane];
            half8 b1  = hp[(kt * 4 + half * 2 + 1) * 64 + lane];
            a00 = __builtin_amdgcn_mfma_f32_16x16x32_f16(av0, b0, a00, 0, 0, 0);
            a01 = __builtin_amdgcn_mfma_f32_16x16x32_f16(av0, b1, a01, 0, 0, 0);
            a10 = __builtin_amdgcn_mfma_f32_16x16x32_f16(av1, b0, a10, 0, 0, 0);
            a11 = __builtin_amdgcn_mfma_f32_16x16x32_f16(av1, b1, a11, 0, 0, 0);
        }
        // k-split reduction 4 -> 2 -> 1 via LDS
        if (ks == 1 || ks == 3) {
            int srow = (ks == 3 ? 2 : 0) + half;
            red4[(srow * 4 + 0) * 64 + lane] = a00;
            red4[(srow * 4 + 1) * 64 + lane] = a01;
            red4[(srow * 4 + 2) * 64 + lane] = a10;
            red4[(srow * 4 + 3) * 64 + lane] = a11;
        }
        __syncthreads();
        if (ks == 0 || ks == 2) {
            int srow = (ks == 2 ? 2 : 0) + half;
            a00 += red4[(srow * 4 + 0) * 64 + lane];
            a01 += red4[(srow * 4 + 1) * 64 + lane];
            a10 += red4[(srow * 4 + 2) * 64 + lane];
            a11 += red4[(srow * 4 + 3) * 64 + lane];
        }
        __syncthreads();
        if (ks == 2) {
            red4[(half * 4 + 0) * 64 + lane] = a00;
            red4[(half * 4 + 1) * 64 + lane] = a01;
            red4[(half * 4 + 2) * 64 + lane] = a10;
            red4[(half * 4 + 3) * 64 + lane] = a11;
        }
        __syncthreads();
        if (ks == 0) {
            a00 += red4[(half * 4 + 0) * 64 + lane];
            a01 += red4[(half * 4 + 1) * 64 + lane];
            a10 += red4[(half * 4 + 2) * 64 + lane];
            a11 += red4[(half * 4 + 3) * 64 + lane];
            const int q = lane >> 4, col = lane & 15;
            #pragma unroll
            for (int r = 0; r < 4; ++r) {
                float* g0 = gates + (q * 4 + r) * 64 + (half * 2) * 16 + col;       // mt=0
                float* g1 = gates + (16 + q * 4 + r) * 64 + (half * 2) * 16 + col;  // mt=1
                g0[0]  = a00[r] + bias_r[0][r];
                g0[16] = a01[r] + bias_r[0][r];
                g1[0]  = a10[r] + bias_r[1][r];
                g1[16] = a11[r] + bias_r[1][r];
            }
        }
        __syncthreads();
        // pointwise: wave w = local unit j, lane = batch b; c in register
        {
            const int b = lane;
            float gi = gates[(0  + w) * 64 + b];
            float gf = gates[(8  + w) * 64 + b];
            float gg = gates[(16 + w) * 64 + b];
            float go = gates[(24 + w) * 64 + b];
            float iv = 1.0f / (1.0f + __expf(-gi));
            float fv = 1.0f / (1.0f + __expf(-gf));
            float eg = __expf(2.0f * gg);
            float gv = 1.0f - 2.0f / (eg + 1.0f);          // tanh(gg)
            float ov = 1.0f / (1.0f + __expf(-go));
            creg = fv * creg + iv * gv;
            float ec = __expf(2.0f * creg);
            float th = 1.0f - 2.0f / (ec + 1.0f);          // tanh(c)
            float hv = ov * th;
            hstage[b * 8 + w] = (_Float16)hv;    // [b][unit], 16 B per batch row
            ybuf[w * 64 + b]  = hv * wj;
        }
        __syncthreads();
        if (w == 0) {
            const int b = lane;
            if (t < steps - 1) {
                // publish h for batch b=lane: this block's 8 units = 16 contiguous
                // bytes of the B-fragment half8 group. Two 8-byte agent-scope
                // relaxed atomic stores (coherence point, no L2 residency).
                const int kt = blk >> 2, quad = blk & 3;       // fixed per block
                const int nt = b >> 4, lp = quad * 16 + (b & 15);
                const size_t g = (size_t)(kt * 4 + nt) * 64 + lp;
                unsigned long long* dst = (unsigned long long*)
                    (hbuf + (size_t)(t + 1) * HID * BATCH + g * 8);
                const unsigned long long* src =
                    (const unsigned long long*)(hstage + b * 8);
                unsigned long long v0 = src[0], v1 = src[1];
                __hip_atomic_store(dst,     v0, __ATOMIC_RELAXED, __HIP_MEMORY_SCOPE_AGENT);
                __hip_atomic_store(dst + 1, v1, __ATOMIC_RELAXED, __HIP_MEMORY_SCOPE_AGENT);
                asm volatile("s_waitcnt vmcnt(0)" ::: "memory");  // h at coherence point
                if (lane == 0)
                    __hip_atomic_store(&flags[blk], (unsigned)(t + 1),
                                       __ATOMIC_RELAXED, __HIP_MEMORY_SCOPE_AGENT);
            }
            // y partial (after flag release: off the critical path)
            float s = ybuf[lane];
            #pragma unroll
            for (int u = 1; u < 8; ++u) s += ybuf[u * 64 + lane];
            ypart[((size_t)t * NCU + blk) * 64 + lane] = s;
        }
        if (t == 0) {
            // upgrade Wlds in place: W_hh -> W_sum (+= W_ih); must complete in
            // ALL waves before any wave's step-1 MFMA -> block barrier after.
            for (int idx = tid; idx < 2 * 64 * 64; idx += 512) {
                int l = idx & 63, kt = (idx >> 6) & 63, m2 = idx >> 12;
                int m = l & 15;
                int gate = m2 * 2 + (m >> 3);
                int row  = gate * HID + blk * 8 + (m & 7);
                int col  = kt * 32 + (l >> 4) * 8;
                const float4* p = (const float4*)(wih + (size_t)row * HID + col);
                float4 a = p[0], b = p[1];
                half8 v = Wlds[idx];
                v[0] = (_Float16)((float)v[0] + a.x); v[1] = (_Float16)((float)v[1] + a.y);
                v[2] = (_Float16)((float)v[2] + a.z); v[3] = (_Float16)((float)v[3] + a.w);
                v[4] = (_Float16)((float)v[4] + b.x); v[5] = (_Float16)((float)v[5] + b.y);
                v[6] = (_Float16)((float)v[6] + b.z); v[7] = (_Float16)((float)v[7] + b.w);
                Wlds[idx] = v;
            }
            __syncthreads();
        }
        if (t < steps - 1) {
            // per-slice wait: this wave consumes only k units [ks*512,(ks+1)*512)
            // = producer blocks [ks*64, ks*64+64). Lane li waits flags[ks*64+li].
            while (__hip_atomic_load(&flags[ks * 64 + lane], __ATOMIC_RELAXED,
                                     __HIP_MEMORY_SCOPE_AGENT) <= (unsigned)t)
                __builtin_amdgcn_s_sleep(1);
            asm volatile("" ::: "memory");   // no h loads hoisted above the spin
        }
    }
}

// ---- final: out[b][t] = bout + sum over 256 CU partials ----
__global__ __launch_bounds__(512)
void k_yout(const float* __restrict__ ypart, const float* __restrict__ bout,
            float* __restrict__ out, int steps) {
    __shared__ float red[8][64];
    int t = blockIdx.x;
    int tid = threadIdx.x;
    int b = tid & 63, ch = tid >> 6;               // 8 chunks x 32 CUs
    const float* p = ypart + (size_t)t * NCU * 64 + b;
    float s = 0.0f;
    #pragma unroll 8
    for (int cu = ch * 32; cu < ch * 32 + 32; ++cu) s += p[(size_t)cu * 64];
    red[ch][b] = s;
    __syncthreads();
    if (tid < 64) {
        float r = bout[0];
        #pragma unroll
        for (int u = 0; u < 8; ++u) r += red[u][tid];
        out[(size_t)tid * steps + t] = r;
    }
}

extern "C" void kernel_launch(void* const* d_in, const int* in_sizes, int n_in,
                              void* d_out, int out_size, void* d_ws, size_t ws_size,
                              hipStream_t stream) {
    const float* token = (const float*)d_in[0];
    const float* wih   = (const float*)d_in[2];
    const float* whh   = (const float*)d_in[3];
    const float* bih   = (const float*)d_in[4];
    const float* bhh   = (const float*)d_in[5];
    const float* wout  = (const float*)d_in[6];
    const float* bout  = (const float*)d_in[7];
    float* out = (float*)d_out;
    const int steps = out_size / BATCH;            // 30

    char* ws = (char*)d_ws;
    size_t off = 0;
    auto carve = [&](size_t bytes) -> void* {
        void* p = ws + off;
        off = (off + bytes + 255) & ~(size_t)255;
        return p;
    };
    _Float16* hbuf  = (_Float16*)carve((size_t)(steps + 1) * HID * BATCH * 2); // ~8 MB
    float*    bsum  = (float*)carve((size_t)G4 * 4);                   // 32 KB
    float*    ypart = (float*)carve((size_t)steps * NCU * 64 * 4);     // ~2 MB
    unsigned* flags = (unsigned*)carve(NCU * 4);

    hipFuncSetAttribute(reinterpret_cast<const void*>(&k_lstm),
                        hipFuncAttributeMaxDynamicSharedMemorySize, LDS_BYTES);

    k_init<<<dim3(HGRP / 256), dim3(256), 0, stream>>>(
        token, bih, bhh, (half8*)hbuf, bsum, flags);

    k_lstm<<<dim3(NCU), dim3(512), LDS_BYTES, stream>>>(
        wih, whh, bsum, wout, hbuf, ypart, flags, steps);

    k_yout<<<dim3(steps), dim3(512), 0, stream>>>(ypart, bout, out, steps);
}